// Round 9
// baseline (150.279 us; speedup 1.0000x reference)
//
#include <hip/hip_runtime.h>

// 9x9 clipped box-SUM on (8,3,1024,1024) f32 — round-4 structure (best:
// 39.4us) + __launch_bounds__(256,8) to force VGPR<=64 -> 32 waves/CU.
//
// Diagnosis history: every variant lands ~39-44us with VALUBusy ~10%, HBM
// ~66% of achievable, 0 bank conflicts -> latency-bound, limited by resident
// waves (16/CU at VGPR 72-120). VGPR=64 is the occupancy-doubling boundary
// (waves/CU halve at 64/128/256). This round changes ONLY the register cap.
//
// Wave = 64 lanes x 4 cols = 256 columns (248 outputs + 4-col halo/side).
// Vertical: rolling 9-row window sum over a 16-row chunk, staged r[25],
// all-static indices (rule #20: no scratch; tripwire = WRITE_SIZE ~97MB —
// if it balloons, the 64-reg cap caused spill and this experiment reverts).
// Horizontal: 8 independent in-wave shuffles, 2-deep add chain. No LDS,
// no barriers.

constexpr int H = 1024, W = 1024;
constexpr int RAD = 4;
constexpr int OUTW = 248;               // (64 - 2 halo lanes) * 4 cols
constexpr int NSTRIP = 5;               // ceil(1024 / 248)
constexpr int CHUNK = 16;
constexpr int NCHUNK = H / CHUNK;       // 64
constexpr int NIMG = 24;                // 8 * 3
constexpr int NROWS = CHUNK + 2 * RAD + 1;  // 25

__global__ __launch_bounds__(256, 8) void box9_kernel(const float* __restrict__ x,
                                                      float* __restrict__ out) {
    const int lane = threadIdx.x & 63;
    const int wid  = blockIdx.x * 4 + (threadIdx.x >> 6);

    const int chunk = wid & (NCHUNK - 1);       // adjacent wids -> adjacent
    const int t     = wid >> 6;                 // chunks: halo rows L2-hot
    const int strip = t % NSTRIP;
    const int img   = t / NSTRIP;

    const int  cs  = strip * OUTW - RAD + lane * 4;   // first col this lane holds
    const bool cok = (cs >= 0) && (cs + 3 < W);       // float4 always 16B-aligned
    const float* xp = x   + (size_t)img * (H * W) + (cok ? cs : 0);
    float*       op = out + (size_t)img * (H * W) + (cok ? cs : 0);

    const int h0 = chunk * CHUNK;

    // Stage the chunk + vertical halo; compiler sinks loads into the loop,
    // keeping a ~9-row live window sized to the 64-VGPR budget.
    float4 r[NROWS];
#pragma unroll
    for (int j = 0; j < NROWS; ++j) {
        const int row = h0 - RAD + j;
        r[j] = (cok && (unsigned)row < (unsigned)H)
             ? *reinterpret_cast<const float4*>(xp + (size_t)row * W)
             : make_float4(0.f, 0.f, 0.f, 0.f);
    }

    // V = vertical 9-row window sum, initialized over rows h0-4 .. h0+4.
    float4 V = make_float4(0.f, 0.f, 0.f, 0.f);
#pragma unroll
    for (int j = 0; j < 9; ++j) {
        V.x += r[j].x; V.y += r[j].y; V.z += r[j].z; V.w += r[j].w;
    }

    const bool sok = cok && (lane >= 1) && (lane <= 62);  // halo lanes don't store

#pragma unroll
    for (int j = 0; j < CHUNK; ++j) {
        // Own prefix/suffix sums of V (3-deep).
        const float p0 = V.x, p1 = p0 + V.y, p2 = p1 + V.z, T = p2 + V.w;
        const float s3 = V.w, s2 = s3 + V.z, s1 = s2 + V.y;
        // 8 INDEPENDENT shuffles: suffixes from left lane, prefixes from right.
        const float L0 = __shfl(T,  lane - 1);
        const float L1 = __shfl(s1, lane - 1);
        const float L2 = __shfl(s2, lane - 1);
        const float L3 = __shfl(s3, lane - 1);
        const float R0 = __shfl(p0, lane + 1);
        const float R1 = __shfl(p1, lane + 1);
        const float R2 = __shfl(p2, lane + 1);
        const float R3 = __shfl(T,  lane + 1);
        float4 o;
        o.x = L0 + T + R0;   // 9-wide horizontal windows for cols cs..cs+3
        o.y = L1 + T + R1;
        o.z = L2 + T + R2;
        o.w = L3 + T + R3;
        if (sok) *reinterpret_cast<float4*>(op + (size_t)(h0 + j) * W) = o;

        // Roll vertical window: add row h0+j+5, drop row h0+j-4 (static idx).
        V.x += r[j + 9].x - r[j].x;
        V.y += r[j + 9].y - r[j].y;
        V.z += r[j + 9].z - r[j].z;
        V.w += r[j + 9].w - r[j].w;
    }
}

extern "C" void kernel_launch(void* const* d_in, const int* in_sizes, int n_in,
                              void* d_out, int out_size, void* d_ws, size_t ws_size,
                              hipStream_t stream) {
    const float* x   = (const float*)d_in[0];
    float*       out = (float*)d_out;
    const int n_waves  = NIMG * NSTRIP * NCHUNK;   // 24*5*64 = 7680
    const int n_blocks = n_waves / 4;              // 1920 blocks -> 30 waves/CU
    box9_kernel<<<dim3(n_blocks), dim3(256), 0, stream>>>(x, out);
}

// Round 10
// 40.944 us; speedup vs baseline: 3.6704x; 3.6704x over previous
//
#include <hip/hip_runtime.h>

// 9x9 clipped box-SUM on (8,3,1024,1024) f32 — round-4 structure (best:
// 39.4us, VGPR=72), CHUNK 16->8 to shrink the live register set BELOW the
// 64-VGPR occupancy-doubling boundary NATURALLY (round 9: forcing it with
// __launch_bounds__(256,8) -> VGPR 32 + 220MB scratch spill, 150us).
//
// Wave = 64 lanes x 4 cols = 256 columns (248 outputs + 4-col halo/side).
// Vertical: rolling 9-row window sum over an 8-row chunk, staged r[17],
// all-static indices (rule #20). Halo re-reads (17 rows per 8 outputs) are
// L2/L3-absorbed — FETCH measured 61MB < 96MB input at CHUNK=32.
// Horizontal: 8 independent in-wave shuffles, 2-deep add chain. No LDS,
// no barriers, no extra per-chunk arrays (rounds 6/7 lesson).
//
// Tripwires: WRITE_SIZE >120MB = spill (revert); VGPR 68-72 = null result.

constexpr int H = 1024, W = 1024;
constexpr int RAD = 4;
constexpr int OUTW = 248;               // (64 - 2 halo lanes) * 4 cols
constexpr int NSTRIP = 5;               // ceil(1024 / 248)
constexpr int CHUNK = 8;
constexpr int NCHUNK = H / CHUNK;       // 128
constexpr int NIMG = 24;                // 8 * 3
constexpr int NROWS = CHUNK + 2 * RAD + 1;  // 17

__global__ __launch_bounds__(256) void box9_kernel(const float* __restrict__ x,
                                                   float* __restrict__ out) {
    const int lane = threadIdx.x & 63;
    const int wid  = blockIdx.x * 4 + (threadIdx.x >> 6);

    const int chunk = wid & (NCHUNK - 1);       // adjacent wids -> adjacent
    const int t     = wid >> 7;                 // chunks: halo rows L2-hot
    const int strip = t % NSTRIP;
    const int img   = t / NSTRIP;

    const int  cs  = strip * OUTW - RAD + lane * 4;   // first col this lane holds
    const bool cok = (cs >= 0) && (cs + 3 < W);       // float4 always 16B-aligned
    const float* xp = x   + (size_t)img * (H * W) + (cok ? cs : 0);
    float*       op = out + (size_t)img * (H * W) + (cok ? cs : 0);

    const int h0 = chunk * CHUNK;

    // Stage chunk + vertical halo: 17 independent 16B loads.
    float4 r[NROWS];
#pragma unroll
    for (int j = 0; j < NROWS; ++j) {
        const int row = h0 - RAD + j;
        r[j] = (cok && (unsigned)row < (unsigned)H)
             ? *reinterpret_cast<const float4*>(xp + (size_t)row * W)
             : make_float4(0.f, 0.f, 0.f, 0.f);
    }

    // V = vertical 9-row window sum, initialized over rows h0-4 .. h0+4.
    float4 V = make_float4(0.f, 0.f, 0.f, 0.f);
#pragma unroll
    for (int j = 0; j < 9; ++j) {
        V.x += r[j].x; V.y += r[j].y; V.z += r[j].z; V.w += r[j].w;
    }

    const bool sok = cok && (lane >= 1) && (lane <= 62);  // halo lanes don't store

#pragma unroll
    for (int j = 0; j < CHUNK; ++j) {
        // Own prefix/suffix sums of V (3-deep).
        const float p0 = V.x, p1 = p0 + V.y, p2 = p1 + V.z, T = p2 + V.w;
        const float s3 = V.w, s2 = s3 + V.z, s1 = s2 + V.y;
        // 8 INDEPENDENT shuffles: suffixes from left lane, prefixes from right.
        const float L0 = __shfl(T,  lane - 1);
        const float L1 = __shfl(s1, lane - 1);
        const float L2 = __shfl(s2, lane - 1);
        const float L3 = __shfl(s3, lane - 1);
        const float R0 = __shfl(p0, lane + 1);
        const float R1 = __shfl(p1, lane + 1);
        const float R2 = __shfl(p2, lane + 1);
        const float R3 = __shfl(T,  lane + 1);
        float4 o;
        o.x = L0 + T + R0;   // 9-wide horizontal windows for cols cs..cs+3
        o.y = L1 + T + R1;
        o.z = L2 + T + R2;
        o.w = L3 + T + R3;
        if (sok) *reinterpret_cast<float4*>(op + (size_t)(h0 + j) * W) = o;

        // Roll vertical window: add row h0+j+5, drop row h0+j-4 (static idx).
        V.x += r[j + 9].x - r[j].x;
        V.y += r[j + 9].y - r[j].y;
        V.z += r[j + 9].z - r[j].z;
        V.w += r[j + 9].w - r[j].w;
    }
}

extern "C" void kernel_launch(void* const* d_in, const int* in_sizes, int n_in,
                              void* d_out, int out_size, void* d_ws, size_t ws_size,
                              hipStream_t stream) {
    const float* x   = (const float*)d_in[0];
    float*       out = (float*)d_out;
    const int n_waves  = NIMG * NSTRIP * NCHUNK;   // 24*5*128 = 15360
    const int n_blocks = n_waves / 4;              // 3840 blocks -> 60 waves/CU
    box9_kernel<<<dim3(n_blocks), dim3(256), 0, stream>>>(x, out);
}